// Round 8
// baseline (328.327 us; speedup 1.0000x reference)
//
#include <hip/hip_runtime.h>
#include <hip/hip_bf16.h>

// Spatial Transformer Layer, fp32 end-to-end.
//  k_conv1: conv7x7(3->8)+bias+relu+BN+maxpool2 -> p1 planar [8][64][109][110pad]
//           (round-5 structure; split into 4 dispatches of 16 images for
//            rocprof visibility; __launch_bounds__(256,8) to request full occ)
//  k_conv2: conv5x5(8->10)+bias+relu+BN+maxpool2 -> p2 [64,52,52,10]
//  k_fc1:   split-K partial GEMM [64,27040]x[27040,32], KC=64 -> partial[423][64][32]
//  k_fc2:   reduce + bias + relu + dense2(32->6) + bias -> theta [64,6]
//  k_sample: affine grid + bilinear sampling -> out [64,224,224,3]

#define NCHUNK 423
#define KC 64

// ---------------- conv1: 7x7, 3->8, relu, BN, maxpool2 ----------------
// Round-5 structure: 256 threads, thread = 2x2 conv = 1 pooled px; per-ci
// 8x8 patch to registers; weights via wave-uniform s_load batches.
__global__ __launch_bounds__(256, 8) void k_conv1(
    const float* __restrict__ x, const float* __restrict__ w,
    const float* __restrict__ bias, const float* __restrict__ g,
    const float* __restrict__ bt, const float* __restrict__ m,
    const float* __restrict__ v, float* __restrict__ out, int zbase) {
  __shared__ float s_in[3][38][42];   // 19152 B
  __shared__ float s_bn[3][8];
  const int tid = threadIdx.x;
  const int bx = blockIdx.x, by = blockIdx.y, b = zbase + blockIdx.z;

  if (tid < 8) {
    float sc = g[tid] * rsqrtf(v[tid] + 1e-3f);
    s_bn[0][tid] = sc;
    s_bn[1][tid] = bt[tid] - m[tid] * sc;
    s_bn[2][tid] = bias[tid];
  }
  const int iy0 = by * 32, ix0 = bx * 32;
  const float* xb = x + (size_t)b * 224 * 224 * 3;
  for (int f = tid; f < 38 * 114; f += 256) {
    int r = f / 114, rem = f - r * 114;
    int q = rem / 3, c = rem - q * 3;
    int gy = iy0 + r; if (gy > 223) gy = 223;
    int gc = ix0 + q; if (gc > 223) gc = 223;
    s_in[c][r][q] = xb[(gy * 224 + gc) * 3 + c];
  }
  __syncthreads();

  const int pxl = tid & 15, pyl = tid >> 4;
  const int lx = 2 * pxl, ly = 2 * pyl;
  float acc[2][2][8];
#pragma unroll
  for (int pr = 0; pr < 2; ++pr)
#pragma unroll
    for (int pc = 0; pc < 2; ++pc)
#pragma unroll
      for (int co = 0; co < 8; ++co) acc[pr][pc][co] = 0.f;

#pragma unroll 1
  for (int ci = 0; ci < 3; ++ci) {
    float rw[8][8];
#pragma unroll
    for (int r = 0; r < 8; ++r)
#pragma unroll
      for (int j = 0; j < 4; ++j) {
        float2 t = *(const float2*)&s_in[ci][ly + r][lx + 2 * j];
        rw[r][2 * j] = t.x; rw[r][2 * j + 1] = t.y;
      }
#pragma unroll
    for (int ky = 0; ky < 7; ++ky) {
      float wv[7][8];
#pragma unroll
      for (int kx = 0; kx < 7; ++kx) {
        const float* wp = w + ((ky * 7 + kx) * 3 + ci) * 8;  // wave-uniform
        float4 a = *(const float4*)wp;
        float4 c4 = *(const float4*)(wp + 4);
        wv[kx][0] = a.x;  wv[kx][1] = a.y;  wv[kx][2] = a.z;  wv[kx][3] = a.w;
        wv[kx][4] = c4.x; wv[kx][5] = c4.y; wv[kx][6] = c4.z; wv[kx][7] = c4.w;
      }
#pragma unroll
      for (int kx = 0; kx < 7; ++kx)
#pragma unroll
        for (int pr = 0; pr < 2; ++pr)
#pragma unroll
          for (int pc = 0; pc < 2; ++pc) {
            float iv = rw[ky + pr][kx + pc];
#pragma unroll
            for (int co = 0; co < 8; ++co)
              acc[pr][pc][co] = fmaf(iv, wv[kx][co], acc[pr][pc][co]);
          }
    }
  }

  const int py = by * 16 + pyl, px = bx * 16 + pxl;
  if (py < 109 && px < 109) {
#pragma unroll
    for (int co = 0; co < 8; ++co) {
      float sc = s_bn[0][co], sh = s_bn[1][co], bs = s_bn[2][co];
      float a0 = fmaxf(acc[0][0][co] + bs, 0.f) * sc + sh;
      float a1 = fmaxf(acc[0][1][co] + bs, 0.f) * sc + sh;
      float a2 = fmaxf(acc[1][0][co] + bs, 0.f) * sc + sh;
      float a3 = fmaxf(acc[1][1][co] + bs, 0.f) * sc + sh;
      out[((size_t)co * 64 + b) * 109 * 110 + py * 110 + px] =
          fmaxf(fmaxf(a0, a1), fmaxf(a2, a3));
    }
  }
}

// ---------------- conv2: 5x5, 8->10, relu, BN, maxpool2 (round-5) ----------
__global__ __launch_bounds__(256) void k_conv2(
    const float* __restrict__ in, const float* __restrict__ w,
    const float* __restrict__ bias, const float* __restrict__ g,
    const float* __restrict__ bt, const float* __restrict__ m,
    const float* __restrict__ v, float* __restrict__ out) {
  __shared__ float s_in[8][36][38];   // 43776 B
  __shared__ float s_bn[3][10];
  const int tid = threadIdx.x;
  const int bx = blockIdx.x, by = blockIdx.y, b = blockIdx.z;

  if (tid < 10) {
    float sc = g[tid] * rsqrtf(v[tid] + 1e-3f);
    s_bn[0][tid] = sc;
    s_bn[1][tid] = bt[tid] - m[tid] * sc;
    s_bn[2][tid] = bias[tid];
  }
  const int iy0 = by * 32, ix0 = bx * 32;
  for (int f = tid; f < 8 * 36 * 36; f += 256) {
    int ci = f / 1296, rem = f - ci * 1296;
    int r = rem / 36, q = rem - r * 36;
    int gy = iy0 + r; if (gy > 108) gy = 108;
    int gc = ix0 + q; if (gc > 108) gc = 108;
    s_in[ci][r][q] = in[(((size_t)ci * 64 + b) * 109 + gy) * 110 + gc];
  }
  __syncthreads();

  const int pxl = tid & 15, pyl = tid >> 4;
  const int lx = 2 * pxl, ly = 2 * pyl;
  float acc[2][2][10];
#pragma unroll
  for (int pr = 0; pr < 2; ++pr)
#pragma unroll
    for (int pc = 0; pc < 2; ++pc)
#pragma unroll
      for (int co = 0; co < 10; ++co) acc[pr][pc][co] = 0.f;

#pragma unroll 1
  for (int ci = 0; ci < 8; ++ci) {
    float rw[6][8];
#pragma unroll
    for (int r = 0; r < 6; ++r)
#pragma unroll
      for (int j = 0; j < 4; ++j) {
        float2 t = *(const float2*)&s_in[ci][ly + r][lx + 2 * j];
        rw[r][2 * j] = t.x; rw[r][2 * j + 1] = t.y;
      }
#pragma unroll
    for (int ky = 0; ky < 5; ++ky) {
      float wv[5][10];
#pragma unroll
      for (int kx = 0; kx < 5; ++kx) {
        const float* wp = w + ((ky * 5 + kx) * 8 + ci) * 10;  // wave-uniform
#pragma unroll
        for (int u = 0; u < 5; ++u) {
          float2 t = *(const float2*)(wp + 2 * u);
          wv[kx][2 * u] = t.x; wv[kx][2 * u + 1] = t.y;
        }
      }
#pragma unroll
      for (int kx = 0; kx < 5; ++kx)
#pragma unroll
        for (int pr = 0; pr < 2; ++pr)
#pragma unroll
          for (int pc = 0; pc < 2; ++pc) {
            float iv = rw[ky + pr][kx + pc];
#pragma unroll
            for (int co = 0; co < 10; ++co)
              acc[pr][pc][co] = fmaf(iv, wv[kx][co], acc[pr][pc][co]);
          }
    }
  }

  const int py = by * 16 + pyl, px = bx * 16 + pxl;
  if (py < 52 && px < 52) {
    float res[10];
#pragma unroll
    for (int co = 0; co < 10; ++co) {
      float sc = s_bn[0][co], sh = s_bn[1][co], bs = s_bn[2][co];
      float a0 = fmaxf(acc[0][0][co] + bs, 0.f) * sc + sh;
      float a1 = fmaxf(acc[0][1][co] + bs, 0.f) * sc + sh;
      float a2 = fmaxf(acc[1][0][co] + bs, 0.f) * sc + sh;
      float a3 = fmaxf(acc[1][1][co] + bs, 0.f) * sc + sh;
      res[co] = fmaxf(fmaxf(a0, a1), fmaxf(a2, a3));
    }
    float2* op2 = (float2*)&out[(((size_t)b * 52 + py) * 52 + px) * 10];
#pragma unroll
    for (int i = 0; i < 5; i++)
      op2[i] = make_float2(res[2 * i], res[2 * i + 1]);
  }
}

// ---------------- fc1 split-K: [64,27040] x [27040,32], KC=64 --------------
__global__ __launch_bounds__(256) void k_fc1(
    const float* __restrict__ act, const float* __restrict__ w,
    float* __restrict__ partial) {
  __shared__ float s_a[64][KC];     // 16 KB
  __shared__ float s_w[KC * 32];    // 8 KB
  const int tid = threadIdx.x;
  const int chunk = blockIdx.x;
  const int k0 = chunk * KC;
  for (int f = tid; f < 64 * KC; f += 256) {
    int row = f >> 6, j = f & (KC - 1);
    int k = k0 + j;
    s_a[row][j] = (k < 27040) ? act[(size_t)row * 27040 + k] : 0.f;
  }
  for (int f = tid; f < KC * 32; f += 256) {
    int k = k0 + (f >> 5);
    s_w[f] = (k < 27040) ? w[(size_t)k0 * 32 + f] : 0.f;
  }
  __syncthreads();
  const int o = tid & 31, gg = tid >> 5;
  float sums[8];
#pragma unroll
  for (int i = 0; i < 8; i++) sums[i] = 0.f;
#pragma unroll 2
  for (int j = 0; j < KC; j += 4) {
    float w0 = s_w[j * 32 + o];
    float w1 = s_w[(j + 1) * 32 + o];
    float w2 = s_w[(j + 2) * 32 + o];
    float w3 = s_w[(j + 3) * 32 + o];
#pragma unroll
    for (int i = 0; i < 8; i++) {
      float4 av = *(const float4*)&s_a[gg * 8 + i][j];
      sums[i] = fmaf(av.x, w0, sums[i]);
      sums[i] = fmaf(av.y, w1, sums[i]);
      sums[i] = fmaf(av.z, w2, sums[i]);
      sums[i] = fmaf(av.w, w3, sums[i]);
    }
  }
#pragma unroll
  for (int i = 0; i < 8; i++)
    partial[((size_t)chunk * 64 + gg * 8 + i) * 32 + o] = sums[i];
}

// ---------------- fc2: reduce, relu, dense2 -> theta [64,6] ----------------
__global__ __launch_bounds__(256) void k_fc2(
    const float* __restrict__ partial, const float* __restrict__ d1b,
    const float* __restrict__ d2w, const float* __restrict__ d2b,
    float* __restrict__ theta) {
  const int b = blockIdx.x;
  const int t = threadIdx.x;
  const int o = t & 31, seg = t >> 5;
  const int c0 = (seg < 7) ? seg * 53 : 371;
  const int cnt = (seg < 7) ? 53 : 52;
  float s = 0.f;
  for (int c = c0; c < c0 + cnt; ++c)
    s += partial[((size_t)c * 64 + b) * 32 + o];
  __shared__ float s_red[8][33];
  s_red[seg][o] = s;
  __syncthreads();
  __shared__ float s_h[32];
  if (t < 32) {
    float tot = 0.f;
#pragma unroll
    for (int sg = 0; sg < 8; ++sg) tot += s_red[sg][t];
    s_h[t] = fmaxf(tot + d1b[t], 0.f);
  }
  __syncthreads();
  if (t < 6) {
    float th = d2b[t];
#pragma unroll
    for (int o2 = 0; o2 < 32; o2++) th = fmaf(s_h[o2], d2w[o2 * 6 + t], th);
    theta[b * 6 + t] = th;
  }
}

// ---------------- sampler: affine grid + bilinear, zero outside ------------
__global__ __launch_bounds__(256) void k_sample(
    const float* __restrict__ x, const float* __restrict__ theta,
    float* __restrict__ out) {
  const int b = blockIdx.y;
  __shared__ float th[6];
  if (threadIdx.x < 6) th[threadIdx.x] = theta[b * 6 + threadIdx.x];
  __syncthreads();
  const int t = blockIdx.x * 256 + threadIdx.x;  // grid sized exactly 50176
  const int oy = t / 224, ox = t - oy * 224;
  const float xn = -1.f + (2.f / 223.f) * (float)ox;
  const float yn = -1.f + (2.f / 223.f) * (float)oy;
  const float cx = th[0] * xn + th[1] * yn + th[2];
  const float cy = th[3] * xn + th[4] * yn + th[5];
  const float px = (cx + 1.f) * 0.5f * 223.f;
  const float py = (cy + 1.f) * 0.5f * 223.f;
  const float x0f = floorf(px), y0f = floorf(py);
  const int x0 = (int)x0f, y0 = (int)y0f;
  const float wx = px - x0f, wy = py - y0f;
  const float* xb = x + (size_t)b * 224 * 224 * 3;
  float a0 = 0.f, a1 = 0.f, a2 = 0.f;
#pragma unroll
  for (int dy = 0; dy < 2; dy++) {
    const int yi = y0 + dy;
    const bool vy = (yi >= 0) && (yi < 224);
    const int yc = yi < 0 ? 0 : (yi > 223 ? 223 : yi);
    const float wyv = dy ? wy : 1.f - wy;
#pragma unroll
    for (int dx = 0; dx < 2; dx++) {
      const int xi = x0 + dx;
      const bool vx = (xi >= 0) && (xi < 224);
      const int xc = xi < 0 ? 0 : (xi > 223 ? 223 : xi);
      const float wv = wyv * (dx ? wx : 1.f - wx) * ((vx && vy) ? 1.f : 0.f);
      const float* p = &xb[(yc * 224 + xc) * 3];
      a0 = fmaf(p[0], wv, a0);
      a1 = fmaf(p[1], wv, a1);
      a2 = fmaf(p[2], wv, a2);
    }
  }
  float* op = &out[((size_t)b * 50176 + t) * 3];
  op[0] = a0; op[1] = a1; op[2] = a2;
}

extern "C" void kernel_launch(void* const* d_in, const int* in_sizes, int n_in,
                              void* d_out, int out_size, void* d_ws, size_t ws_size,
                              hipStream_t stream) {
  const float* x    = (const float*)d_in[0];
  const float* c1w  = (const float*)d_in[1];
  const float* c1b  = (const float*)d_in[2];
  const float* g1   = (const float*)d_in[3];
  const float* b1   = (const float*)d_in[4];
  const float* m1   = (const float*)d_in[5];
  const float* v1   = (const float*)d_in[6];
  const float* c2w  = (const float*)d_in[7];
  const float* c2b  = (const float*)d_in[8];
  const float* g2   = (const float*)d_in[9];
  const float* b2   = (const float*)d_in[10];
  const float* m2   = (const float*)d_in[11];
  const float* v2   = (const float*)d_in[12];
  const float* d1w  = (const float*)d_in[13];
  const float* d1b  = (const float*)d_in[14];
  const float* d2w  = (const float*)d_in[15];
  const float* d2b  = (const float*)d_in[16];
  float* out = (float*)d_out;

  float* ws = (float*)d_ws;
  float* p1    = ws;                    // 8*64*109*110 = 6,138,880 floats (planar, padded)
  float* p2    = p1 + 6138880;          // 64*52*52*10  = 1,730,560 floats
  float* theta = p2 + 1730560;          // 384 floats
  float* part  = ws;                    // overlaps p1 (dead after conv2): 423*64*32 = 866,304

  // conv1 split into 4 dispatches of 16 images (diagnostic: lets other
  // kernels surface in the rocprof top-5; same total work).
  for (int zb = 0; zb < 64; zb += 16)
    k_conv1<<<dim3(7, 7, 16), 256, 0, stream>>>(x, c1w, c1b, g1, b1, m1, v1, p1, zb);
  k_conv2<<<dim3(4, 4, 64), 256, 0, stream>>>(p1, c2w, c2b, g2, b2, m2, v2, p2);
  k_fc1<<<NCHUNK, 256, 0, stream>>>(p2, d1w, part);
  k_fc2<<<64, 256, 0, stream>>>(part, d1b, d2w, d2b, theta);
  k_sample<<<dim3(196, 64), 256, 0, stream>>>(x, theta, out);
}

// Round 9
// 275.271 us; speedup vs baseline: 1.1927x; 1.1927x over previous
//
#include <hip/hip_runtime.h>
#include <hip/hip_bf16.h>

// Spatial Transformer Layer, fp32 end-to-end.
//  k_conv1: conv7x7(3->8)+bias+relu+BN+maxpool2 -> p1 planar [8][64][109][110pad]
//           (round-5 proven kernel, single dispatch)
//  k_conv2: conv5x5(8->10)+bias+relu+BN+maxpool2 -> p2 [64,52,52,10]
//           (round-9: 52x4 pooled strip/block, 2-phase ci staging, 21 KB LDS)
//  k_fc1:   split-K partial GEMM [64,27040]x[27040,32], KC=64 -> partial[423][64][32]
//  k_fc2:   reduce + bias + relu + dense2(32->6) + bias -> theta [64,6]
//  k_sample: affine grid + bilinear sampling, 2 px/thread -> out [64,224,224,3]

#define NCHUNK 423
#define KC 64

// ---------------- conv1: 7x7, 3->8, relu, BN, maxpool2 (round-5) -----------
__global__ __launch_bounds__(256) void k_conv1(
    const float* __restrict__ x, const float* __restrict__ w,
    const float* __restrict__ bias, const float* __restrict__ g,
    const float* __restrict__ bt, const float* __restrict__ m,
    const float* __restrict__ v, float* __restrict__ out) {
  __shared__ float s_in[3][38][42];   // 19152 B
  __shared__ float s_bn[3][8];
  const int tid = threadIdx.x;
  const int bx = blockIdx.x, by = blockIdx.y, b = blockIdx.z;

  if (tid < 8) {
    float sc = g[tid] * rsqrtf(v[tid] + 1e-3f);
    s_bn[0][tid] = sc;
    s_bn[1][tid] = bt[tid] - m[tid] * sc;
    s_bn[2][tid] = bias[tid];
  }
  const int iy0 = by * 32, ix0 = bx * 32;
  const float* xb = x + (size_t)b * 224 * 224 * 3;
  for (int f = tid; f < 38 * 114; f += 256) {
    int r = f / 114, rem = f - r * 114;
    int q = rem / 3, c = rem - q * 3;
    int gy = iy0 + r; if (gy > 223) gy = 223;
    int gc = ix0 + q; if (gc > 223) gc = 223;
    s_in[c][r][q] = xb[(gy * 224 + gc) * 3 + c];
  }
  __syncthreads();

  const int pxl = tid & 15, pyl = tid >> 4;
  const int lx = 2 * pxl, ly = 2 * pyl;
  float acc[2][2][8];
#pragma unroll
  for (int pr = 0; pr < 2; ++pr)
#pragma unroll
    for (int pc = 0; pc < 2; ++pc)
#pragma unroll
      for (int co = 0; co < 8; ++co) acc[pr][pc][co] = 0.f;

#pragma unroll 1
  for (int ci = 0; ci < 3; ++ci) {
    float rw[8][8];
#pragma unroll
    for (int r = 0; r < 8; ++r)
#pragma unroll
      for (int j = 0; j < 4; ++j) {
        float2 t = *(const float2*)&s_in[ci][ly + r][lx + 2 * j];
        rw[r][2 * j] = t.x; rw[r][2 * j + 1] = t.y;
      }
#pragma unroll
    for (int ky = 0; ky < 7; ++ky) {
      float wv[7][8];
#pragma unroll
      for (int kx = 0; kx < 7; ++kx) {
        const float* wp = w + ((ky * 7 + kx) * 3 + ci) * 8;  // wave-uniform
        float4 a = *(const float4*)wp;
        float4 c4 = *(const float4*)(wp + 4);
        wv[kx][0] = a.x;  wv[kx][1] = a.y;  wv[kx][2] = a.z;  wv[kx][3] = a.w;
        wv[kx][4] = c4.x; wv[kx][5] = c4.y; wv[kx][6] = c4.z; wv[kx][7] = c4.w;
      }
#pragma unroll
      for (int kx = 0; kx < 7; ++kx)
#pragma unroll
        for (int pr = 0; pr < 2; ++pr)
#pragma unroll
          for (int pc = 0; pc < 2; ++pc) {
            float iv = rw[ky + pr][kx + pc];
#pragma unroll
            for (int co = 0; co < 8; ++co)
              acc[pr][pc][co] = fmaf(iv, wv[kx][co], acc[pr][pc][co]);
          }
    }
  }

  const int py = by * 16 + pyl, px = bx * 16 + pxl;
  if (py < 109 && px < 109) {
#pragma unroll
    for (int co = 0; co < 8; ++co) {
      float sc = s_bn[0][co], sh = s_bn[1][co], bs = s_bn[2][co];
      float a0 = fmaxf(acc[0][0][co] + bs, 0.f) * sc + sh;
      float a1 = fmaxf(acc[0][1][co] + bs, 0.f) * sc + sh;
      float a2 = fmaxf(acc[1][0][co] + bs, 0.f) * sc + sh;
      float a3 = fmaxf(acc[1][1][co] + bs, 0.f) * sc + sh;
      out[((size_t)co * 64 + b) * 109 * 110 + py * 110 + px] =
          fmaxf(fmaxf(a0, a1), fmaxf(a2, a3));
    }
  }
}

// ---------------- conv2: 5x5, 8->10, relu, BN, maxpool2 --------------------
// Round-9: block = 52x4 pooled strip (64x4 thread layout, tx<52 active),
// grid (13, 64). 2 phases of 4 input channels; LDS 21.1 KB/phase.
__global__ __launch_bounds__(256) void k_conv2(
    const float* __restrict__ in, const float* __restrict__ w,
    const float* __restrict__ bias, const float* __restrict__ g,
    const float* __restrict__ bt, const float* __restrict__ m,
    const float* __restrict__ v, float* __restrict__ out) {
  __shared__ float s_in[4][12][110];   // 21120 B
  __shared__ float s_bn[3][10];
  const int tid = threadIdx.x;
  const int by = blockIdx.x, b = blockIdx.y;

  if (tid < 10) {
    float sc = g[tid] * rsqrtf(v[tid] + 1e-3f);
    s_bn[0][tid] = sc;
    s_bn[1][tid] = bt[tid] - m[tid] * sc;
    s_bn[2][tid] = bias[tid];
  }
  const int iy0 = by * 8;              // conv-row base; rows iy0..iy0+11 (<=107)
  const int tx = tid & 63, ty = tid >> 6;
  const int lx = 2 * tx, ly = 2 * ty;
  const bool active = tx < 52;
  float acc[2][2][10];
#pragma unroll
  for (int pr = 0; pr < 2; ++pr)
#pragma unroll
    for (int pc = 0; pc < 2; ++pc)
#pragma unroll
      for (int co = 0; co < 10; ++co) acc[pr][pc][co] = 0.f;

#pragma unroll 1
  for (int ph = 0; ph < 2; ++ph) {
    if (ph) __syncthreads();           // protect buffer overwrite
    for (int f = tid; f < 4 * 12 * 108; f += 256) {
      int c = f / 1296, rem = f - c * 1296;
      int r = rem / 108, q = rem - r * 108;
      s_in[c][r][q] = in[(((size_t)(ph * 4 + c) * 64 + b) * 109 + iy0 + r) * 110 + q];
    }
    __syncthreads();

    if (active) {
#pragma unroll 1
      for (int c = 0; c < 4; ++c) {
        float rw[6][8];
#pragma unroll
        for (int r = 0; r < 6; ++r)
#pragma unroll
          for (int j = 0; j < 4; ++j) {
            float2 t = *(const float2*)&s_in[c][ly + r][lx + 2 * j];
            rw[r][2 * j] = t.x; rw[r][2 * j + 1] = t.y;
          }
#pragma unroll
        for (int ky = 0; ky < 5; ++ky) {
          float wv[5][10];
#pragma unroll
          for (int kx = 0; kx < 5; ++kx) {
            const float* wp = w + ((ky * 5 + kx) * 8 + ph * 4 + c) * 10;  // uniform
#pragma unroll
            for (int u = 0; u < 5; ++u) {
              float2 t = *(const float2*)(wp + 2 * u);
              wv[kx][2 * u] = t.x; wv[kx][2 * u + 1] = t.y;
            }
          }
#pragma unroll
          for (int kx = 0; kx < 5; ++kx)
#pragma unroll
            for (int pr = 0; pr < 2; ++pr)
#pragma unroll
              for (int pc = 0; pc < 2; ++pc) {
                float iv = rw[ky + pr][kx + pc];
#pragma unroll
                for (int co = 0; co < 10; ++co)
                  acc[pr][pc][co] = fmaf(iv, wv[kx][co], acc[pr][pc][co]);
              }
        }
      }
    }
  }

  if (active) {
    const int py = by * 4 + ty, px = tx;   // py 0..51, px 0..51
    float res[10];
#pragma unroll
    for (int co = 0; co < 10; ++co) {
      float sc = s_bn[0][co], sh = s_bn[1][co], bs = s_bn[2][co];
      float a0 = fmaxf(acc[0][0][co] + bs, 0.f) * sc + sh;
      float a1 = fmaxf(acc[0][1][co] + bs, 0.f) * sc + sh;
      float a2 = fmaxf(acc[1][0][co] + bs, 0.f) * sc + sh;
      float a3 = fmaxf(acc[1][1][co] + bs, 0.f) * sc + sh;
      res[co] = fmaxf(fmaxf(a0, a1), fmaxf(a2, a3));
    }
    float2* op2 = (float2*)&out[(((size_t)b * 52 + py) * 52 + px) * 10];
#pragma unroll
    for (int i = 0; i < 5; i++)
      op2[i] = make_float2(res[2 * i], res[2 * i + 1]);
  }
}

// ---------------- fc1 split-K: [64,27040] x [27040,32], KC=64 --------------
__global__ __launch_bounds__(256) void k_fc1(
    const float* __restrict__ act, const float* __restrict__ w,
    float* __restrict__ partial) {
  __shared__ float s_a[64][KC];     // 16 KB
  __shared__ float s_w[KC * 32];    // 8 KB
  const int tid = threadIdx.x;
  const int chunk = blockIdx.x;
  const int k0 = chunk * KC;
  for (int f = tid; f < 64 * KC; f += 256) {
    int row = f >> 6, j = f & (KC - 1);
    int k = k0 + j;
    s_a[row][j] = (k < 27040) ? act[(size_t)row * 27040 + k] : 0.f;
  }
  for (int f = tid; f < KC * 32; f += 256) {
    int k = k0 + (f >> 5);
    s_w[f] = (k < 27040) ? w[(size_t)k0 * 32 + f] : 0.f;
  }
  __syncthreads();
  const int o = tid & 31, gg = tid >> 5;
  float sums[8];
#pragma unroll
  for (int i = 0; i < 8; i++) sums[i] = 0.f;
#pragma unroll 2
  for (int j = 0; j < KC; j += 4) {
    float w0 = s_w[j * 32 + o];
    float w1 = s_w[(j + 1) * 32 + o];
    float w2 = s_w[(j + 2) * 32 + o];
    float w3 = s_w[(j + 3) * 32 + o];
#pragma unroll
    for (int i = 0; i < 8; i++) {
      float4 av = *(const float4*)&s_a[gg * 8 + i][j];
      sums[i] = fmaf(av.x, w0, sums[i]);
      sums[i] = fmaf(av.y, w1, sums[i]);
      sums[i] = fmaf(av.z, w2, sums[i]);
      sums[i] = fmaf(av.w, w3, sums[i]);
    }
  }
#pragma unroll
  for (int i = 0; i < 8; i++)
    partial[((size_t)chunk * 64 + gg * 8 + i) * 32 + o] = sums[i];
}

// ---------------- fc2: reduce, relu, dense2 -> theta [64,6] ----------------
__global__ __launch_bounds__(256) void k_fc2(
    const float* __restrict__ partial, const float* __restrict__ d1b,
    const float* __restrict__ d2w, const float* __restrict__ d2b,
    float* __restrict__ theta) {
  const int b = blockIdx.x;
  const int t = threadIdx.x;
  const int o = t & 31, seg = t >> 5;
  const int c0 = (seg < 7) ? seg * 53 : 371;
  const int cnt = (seg < 7) ? 53 : 52;
  float s = 0.f;
  for (int c = c0; c < c0 + cnt; ++c)
    s += partial[((size_t)c * 64 + b) * 32 + o];
  __shared__ float s_red[8][33];
  s_red[seg][o] = s;
  __syncthreads();
  __shared__ float s_h[32];
  if (t < 32) {
    float tot = 0.f;
#pragma unroll
    for (int sg = 0; sg < 8; ++sg) tot += s_red[sg][t];
    s_h[t] = fmaxf(tot + d1b[t], 0.f);
  }
  __syncthreads();
  if (t < 6) {
    float th = d2b[t];
#pragma unroll
    for (int o2 = 0; o2 < 32; o2++) th = fmaf(s_h[o2], d2w[o2 * 6 + t], th);
    theta[b * 6 + t] = th;
  }
}

// ---------------- sampler: affine grid + bilinear, 2 px/thread -------------
__global__ __launch_bounds__(256) void k_sample(
    const float* __restrict__ x, const float* __restrict__ theta,
    float* __restrict__ out) {
  const int b = blockIdx.y;
  __shared__ float th[6];
  if (threadIdx.x < 6) th[threadIdx.x] = theta[b * 6 + threadIdx.x];
  __syncthreads();
  const int t0 = (blockIdx.x * 256 + threadIdx.x) * 2;  // grid covers 50176
  const float* xb = x + (size_t)b * 224 * 224 * 3;
  float res[2][3];
#pragma unroll
  for (int i = 0; i < 2; ++i) {
    const int t = t0 + i;
    const int oy = t / 224, ox = t - oy * 224;
    const float xn = -1.f + (2.f / 223.f) * (float)ox;
    const float yn = -1.f + (2.f / 223.f) * (float)oy;
    const float cx = th[0] * xn + th[1] * yn + th[2];
    const float cy = th[3] * xn + th[4] * yn + th[5];
    const float px = (cx + 1.f) * 0.5f * 223.f;
    const float py = (cy + 1.f) * 0.5f * 223.f;
    const float x0f = floorf(px), y0f = floorf(py);
    const int x0 = (int)x0f, y0 = (int)y0f;
    const float wx = px - x0f, wy = py - y0f;
    float a0 = 0.f, a1 = 0.f, a2 = 0.f;
#pragma unroll
    for (int dy = 0; dy < 2; dy++) {
      const int yi = y0 + dy;
      const bool vy = (yi >= 0) && (yi < 224);
      const int yc = yi < 0 ? 0 : (yi > 223 ? 223 : yi);
      const float wyv = dy ? wy : 1.f - wy;
#pragma unroll
      for (int dx = 0; dx < 2; dx++) {
        const int xi = x0 + dx;
        const bool vx = (xi >= 0) && (xi < 224);
        const int xc = xi < 0 ? 0 : (xi > 223 ? 223 : xi);
        const float wv = wyv * (dx ? wx : 1.f - wx) * ((vx && vy) ? 1.f : 0.f);
        const float* p = &xb[(yc * 224 + xc) * 3];
        a0 = fmaf(p[0], wv, a0);
        a1 = fmaf(p[1], wv, a1);
        a2 = fmaf(p[2], wv, a2);
      }
    }
    res[i][0] = a0; res[i][1] = a1; res[i][2] = a2;
  }
  float2* op = (float2*)&out[((size_t)b * 50176 + t0) * 3];
  op[0] = make_float2(res[0][0], res[0][1]);
  op[1] = make_float2(res[0][2], res[1][0]);
  op[2] = make_float2(res[1][1], res[1][2]);
}

extern "C" void kernel_launch(void* const* d_in, const int* in_sizes, int n_in,
                              void* d_out, int out_size, void* d_ws, size_t ws_size,
                              hipStream_t stream) {
  const float* x    = (const float*)d_in[0];
  const float* c1w  = (const float*)d_in[1];
  const float* c1b  = (const float*)d_in[2];
  const float* g1   = (const float*)d_in[3];
  const float* b1   = (const float*)d_in[4];
  const float* m1   = (const float*)d_in[5];
  const float* v1   = (const float*)d_in[6];
  const float* c2w  = (const float*)d_in[7];
  const float* c2b  = (const float*)d_in[8];
  const float* g2   = (const float*)d_in[9];
  const float* b2   = (const float*)d_in[10];
  const float* m2   = (const float*)d_in[11];
  const float* v2   = (const float*)d_in[12];
  const float* d1w  = (const float*)d_in[13];
  const float* d1b  = (const float*)d_in[14];
  const float* d2w  = (const float*)d_in[15];
  const float* d2b  = (const float*)d_in[16];
  float* out = (float*)d_out;

  float* ws = (float*)d_ws;
  float* p1    = ws;                    // 8*64*109*110 = 6,138,880 floats (planar, padded)
  float* p2    = p1 + 6138880;          // 64*52*52*10  = 1,730,560 floats
  float* theta = p2 + 1730560;          // 384 floats
  float* part  = ws;                    // overlaps p1 (dead after conv2): 423*64*32 = 866,304

  k_conv1<<<dim3(7, 7, 64), 256, 0, stream>>>(x, c1w, c1b, g1, b1, m1, v1, p1);
  k_conv2<<<dim3(13, 64), 256, 0, stream>>>(p1, c2w, c2b, g2, b2, m2, v2, p2);
  k_fc1<<<NCHUNK, 256, 0, stream>>>(p2, d1w, part);
  k_fc2<<<64, 256, 0, stream>>>(part, d1b, d2w, d2b, theta);
  k_sample<<<dim3(98, 64), 256, 0, stream>>>(x, theta, out);
}